// Round 12
// baseline (420.694 us; speedup 1.0000x reference)
//
#include <hip/hip_runtime.h>

#define H 64

typedef __attribute__((ext_vector_type(8))) __bf16 bf16x8;
typedef __attribute__((ext_vector_type(4))) float f32x4;
typedef unsigned short u16;
typedef unsigned int u32;

union F8 { bf16x8 b; u16 u[8]; uint4 q; };

// Hardware bf16 convert (v_cvt on gfx950; RNE).
__device__ __forceinline__ u16 f2bf(float f) {
    union { __bf16 h; u16 u; } v; v.h = (__bf16)f; return v.u;
}
__device__ __forceinline__ float bf2f(u16 x) {
    return __uint_as_float((u32)x << 16);
}
// Swizzled layout: element (col,k) at byte ((col*K+k)*2) ^ ((col&7)<<4).
__device__ __forceinline__ unsigned swz(int col, int k, int K) {
    return ((unsigned)(col * K + k) * 2u) ^ (((unsigned)col & 7u) << 4);
}

// ---------------- weight convert (fallback path) ----------------
struct Seg { const float* src; unsigned dstBytes; int K; int N; };
struct Segs { Seg s[8]; };

__global__ __launch_bounds__(256) void conv_weights(Segs segs, char* out) {
    Seg sg = segs.s[blockIdx.y];
    int total = sg.K * sg.N;
    char* dst = out + sg.dstBytes;
    for (int e = blockIdx.x * 256 + threadIdx.x; e < total; e += gridDim.x * 256) {
        int k = e / sg.N, n = e % sg.N;
        *(u16*)(dst + swz(n, k, sg.K)) = f2bf(sg.src[e]);
    }
}

// ---- prep: fused node convert + weight convert + cnt zero (1 launch) ----
struct PrepA { const float4* nsrc; ushort4* ndst; int n4; Segs segs; char* wout; u32* cnt; int N; };

__global__ __launch_bounds__(256) void prep_kernel(PrepA a) {
    if (blockIdx.y == 0) {
        for (int i = blockIdx.x * 256 + threadIdx.x; i < a.n4; i += gridDim.x * 256) {
            float4 f = a.nsrc[i];
            ushort4 o;
            o.x = f2bf(f.x); o.y = f2bf(f.y); o.z = f2bf(f.z); o.w = f2bf(f.w);
            a.ndst[i] = o;
        }
    } else if (blockIdx.y == 1) {
        for (int s = 0; s < 8; ++s) {
            Seg sg = a.segs.s[s];
            int total = sg.K * sg.N;
            char* dst = a.wout + sg.dstBytes;
            for (int e = blockIdx.x * 256 + threadIdx.x; e < total; e += gridDim.x * 256) {
                int k = e / sg.N, n = e % sg.N;
                *(u16*)(dst + swz(n, k, sg.K)) = f2bf(sg.src[e]);
            }
        }
    } else {
        for (int i = blockIdx.x * 256 + threadIdx.x; i < a.N; i += gridDim.x * 256)
            a.cnt[i] = 0u;
    }
}

// ---------------- scan (3 kernels) ----------------
__global__ __launch_bounds__(512) void scan_blocks(u32* __restrict__ data,
                                                   u32* __restrict__ sums, int n) {
    __shared__ u32 s[512];
    int tid = threadIdx.x, i = blockIdx.x * 512 + tid;
    u32 v = (i < n) ? data[i] : 0u;
    s[tid] = v; __syncthreads();
    for (int d = 1; d < 512; d <<= 1) {
        u32 t = (tid >= d) ? s[tid - d] : 0u; __syncthreads();
        s[tid] += t; __syncthreads();
    }
    if (i < n) data[i] = s[tid] - v;               // exclusive
    if (tid == 511) sums[blockIdx.x] = s[511];
}

__global__ __launch_bounds__(512) void scan_sums(u32* __restrict__ sums, int nb) {
    __shared__ u32 s[512];
    int tid = threadIdx.x;
    u32 v = (tid < nb) ? sums[tid] : 0u;
    s[tid] = v; __syncthreads();
    for (int d = 1; d < 512; d <<= 1) {
        u32 t = (tid >= d) ? s[tid - d] : 0u; __syncthreads();
        s[tid] += t; __syncthreads();
    }
    if (tid < nb) sums[tid] = s[tid] - v;          // exclusive
}

__global__ __launch_bounds__(512) void scan_add(u32* __restrict__ data,
                                                const u32* __restrict__ sums, int n) {
    int i = blockIdx.x * 512 + threadIdx.x;
    if (i < n) data[i] += sums[blockIdx.x];
}

// ---- ord scatter (fallback path): ord[base[node] + pre[m]] = m ----
struct OFix {
    const int* idx0; const int* idx1; const int* idx2;
    int m0, m1, m2;
    const u32* base; const u32* pre; u32* ord;
};

__global__ __launch_bounds__(256) void ord_fix(OFix a) {
    const int Mtot = a.m0 + a.m1 + a.m2;
    for (int e = blockIdx.x * 256 + threadIdx.x; e < Mtot; e += gridDim.x * 256) {
        int lm = e, node;
        if (lm < a.m0) node = a.idx0[lm];
        else { lm -= a.m0; if (lm < a.m1) node = a.idx1[lm]; else node = a.idx2[lm - a.m1]; }
        a.ord[a.base[node] + a.pre[e]] = (u32)e;
    }
}

// ---- message permute: msgs[base[node]+pre[e]] = msgu[e] ----
struct Scat {
    const int* idx0; const int* idx1; const int* idx2;
    int m0, m1, m2;
    const u32* base; const u32* pre;
    const u16* msgu; u16* msgs;
};

__global__ __launch_bounds__(256) void scatter_msg(Scat a) {
    const int Mtot = a.m0 + a.m1 + a.m2;
    const int CH = Mtot * 8;                       // 16B chunks
    for (int c = blockIdx.x * 256 + threadIdx.x; c < CH; c += gridDim.x * 256) {
        const int e = c >> 3, q = c & 7;
        int lm = e, node;
        if (lm < a.m0) node = a.idx0[lm];
        else { lm -= a.m0; if (lm < a.m1) node = a.idx1[lm]; else node = a.idx2[lm - a.m1]; }
        const u32 slot = a.base[node] + a.pre[e];
        ((uint4*)(a.msgs + (size_t)slot * 64))[q] =
            ((const uint4*)(a.msgu + (size_t)e * 64))[q];
    }
}

// ============ msg body: fused 2-layer MLP -> UNSORTED msg rows ============
// R25: 1024-thread blocks (16 waves) at the SAME 72KB LDS -> 2 blocks/CU =
// 32 waves/CU (was 16). Per-thread register state identical to R24 (RF=2,
// per-j acc) -- occupancy doubles via wave count, not per-wave work (the
// spill-safe direction; R14/R17/R23 all spilled when per-thread state grew).
// Geometry: A=3: 4 rowgroups x 4 colgroups (NTW=1/chunk); A=2: 4x4 (NTW=2);
// A=1: 256-atom tile, 8 rowgroups x 2 colgroups.
template<int A>
__device__ __forceinline__ void msg_body(
    const u16* __restrict__ nsb, const int* __restrict__ idx,
    const u16* __restrict__ w1T, const float* __restrict__ b1,
    const u16* __restrict__ w2T, const float* __restrict__ b2,
    u16* __restrict__ msgR, int T, int bid, u16* Wl, u16* h1)
{
    constexpr int D    = A * 64;
    constexpr int KS   = D / 32;
    constexpr int NT   = D / 16;
    constexpr bool DUAL = (A == 1);
    constexpr int TILE = DUAL ? 256 : 128;
    constexpr int WH   = (A == 3) ? 3 : 1;  // W column-chunks
    constexpr int NTH  = NT / WH;           // col tiles per chunk
    constexpr int CG   = DUAL ? 2 : 4;      // colgroups
    constexpr int NTW  = NTH / CG;          // col tiles per wave per chunk
    constexpr int COLH = D / WH;
    constexpr int NV4  = (DUAL ? 2 * D * D : COLH * D) / 8;  // uint4 per stage
    constexpr int NB   = WH * NTW;          // bias entries per wave

    const int tid  = threadIdx.x;
    const int lane = tid & 63;
    const int w    = tid >> 6;
    const int g    = lane >> 4;
    const int lr   = lane & 15;
    const int rg   = w / CG;                // rowgroup (rows rg*32 .. +32)
    const int cg   = w % CG;                // colgroup

    const int tile = bid * TILE;

    auto stage = [&](const u16* gsrc) {
#pragma unroll
        for (int i = 0; i < (NV4 + 1023) / 1024; ++i) {
            const int ob = i * 1024 + (w << 6);      // wave-uniform base (uint4)
            if (ob < NV4) {
                const u16* gp = gsrc + ((i * 1024 + tid) << 3);
                u16* lp = Wl + ((size_t)ob << 3);
                __builtin_amdgcn_global_load_lds(
                    (const __attribute__((address_space(1))) void*)gp,
                    (__attribute__((address_space(3))) void*)lp, 16, 0, 0);
            }
        }
    };

    // A-fragment gather (bf16), 2 row-frags per wave
    bf16x8 a1[2][KS];
#pragma unroll
    for (int rf = 0; rf < 2; ++rf) {
        const int trow = tile + rg * 32 + rf * 16 + lr;
        const int tl   = trow < T ? trow : T - 1;
        int nodes[A];
#pragma unroll
        for (int s = 0; s < A; ++s) nodes[s] = idx[(long)tl * A + s];
#pragma unroll
        for (int kk = 0; kk < KS; ++kk) {
            const u16* p = nsb + (long)nodes[kk >> 1] * H + ((kk & 1) * 32 + g * 8);
            F8 t; t.q = *(const uint4*)p;
            a1[rf][kk] = t.b;
        }
    }

    float bias1[NB], bias2[NB];
#pragma unroll
    for (int i = 0; i < NB; ++i) {
        const int jg = (i / NTW) * NTH + cg * NTW + (i % NTW);
        bias1[i] = b1[jg * 16 + lr];
        bias2[i] = b2[jg * 16 + lr];
    }

    // ---- GEMM1 over W1 column-chunks ----
#pragma unroll
    for (int hh = 0; hh < WH; ++hh) {
        stage(DUAL ? w1T : (w1T + (size_t)hh * COLH * D));
        asm volatile("s_waitcnt vmcnt(0)" ::: "memory");
        __syncthreads();                           // chunk resident

#pragma unroll
        for (int jl = 0; jl < NTW; ++jl) {
            const int jc = cg * NTW + jl;          // col tile within chunk
            const int jg = hh * NTH + jc;
            f32x4 acc0 = {0.f, 0.f, 0.f, 0.f};
            f32x4 acc1 = {0.f, 0.f, 0.f, 0.f};
#pragma unroll
            for (int kk = 0; kk < KS; ++kk) {
                F8 bf; bf.q = *(const uint4*)((const char*)Wl + swz(jc * 16 + lr, kk * 32 + g * 8, D));
                acc0 = __builtin_amdgcn_mfma_f32_16x16x32_bf16(a1[0][kk], bf.b, acc0, 0, 0, 0);
                acc1 = __builtin_amdgcn_mfma_f32_16x16x32_bf16(a1[1][kk], bf.b, acc1, 0, 0, 0);
            }
#pragma unroll
            for (int r = 0; r < 4; ++r) {
                const int row0 = rg * 32 + g * 4 + r;
                float v0 = acc0[r] + bias1[hh * NTW + jl]; v0 = v0 > 0.f ? v0 : 0.f;
                float v1 = acc1[r] + bias1[hh * NTW + jl]; v1 = v1 > 0.f ? v1 : 0.f;
                *(u16*)((char*)h1 + swz(row0,      jg * 16 + lr, D)) = f2bf(v0);
                *(u16*)((char*)h1 + swz(row0 + 16, jg * 16 + lr, D)) = f2bf(v1);
            }
        }
        __syncthreads();   // h1 chunk-writes visible; Wl reads done (cross-wave cols)
    }

    // a2 fragments: wave's 32 h1 rows, full D (cross-colgroup data; ordered by
    // the post-GEMM1 barrier)
    bf16x8 a2[2][KS];
#pragma unroll
    for (int rf = 0; rf < 2; ++rf) {
        const int row = rg * 32 + rf * 16 + lr;
#pragma unroll
        for (int kk = 0; kk < KS; ++kk) {
            F8 t; t.q = *(const uint4*)((const char*)h1 + swz(row, kk * 32 + g * 8, D));
            a2[rf][kk] = t.b;
        }
    }
    if constexpr (DUAL) __syncthreads();   // a2 reads done before staging overwrites h1

    // ---- GEMM2 over W2 column-chunks -> stage msg rows into h1 region ----
#pragma unroll
    for (int hh = 0; hh < WH; ++hh) {
        if constexpr (!DUAL) {
            stage(w2T + (size_t)hh * COLH * D);
            asm volatile("s_waitcnt vmcnt(0)" ::: "memory");
            __syncthreads();                       // chunk resident; a2 reads done
        }
        const char* W2base = DUAL ? (const char*)(Wl + D * D) : (const char*)Wl;

#pragma unroll
        for (int jl = 0; jl < NTW; ++jl) {
            const int jc = cg * NTW + jl;
            const int jg = hh * NTH + jc;
            f32x4 acc0 = {0.f, 0.f, 0.f, 0.f};
            f32x4 acc1 = {0.f, 0.f, 0.f, 0.f};
#pragma unroll
            for (int kk = 0; kk < KS; ++kk) {
                F8 bf; bf.q = *(const uint4*)(W2base + swz(jc * 16 + lr, kk * 32 + g * 8, D));
                acc0 = __builtin_amdgcn_mfma_f32_16x16x32_bf16(a2[0][kk], bf.b, acc0, 0, 0, 0);
                acc1 = __builtin_amdgcn_mfma_f32_16x16x32_bf16(a2[1][kk], bf.b, acc1, 0, 0, 0);
            }
            const int gc   = jg * 16 + lr;
            const int slot = gc >> 6;
            const int cs_  = gc & 63;
#pragma unroll
            for (int r = 0; r < 4; ++r) {
                const int a0 = rg * 32 + g * 4 + r;
                const int m0 = a0 * A + slot;
                const int m1 = (a0 + 16) * A + slot;
                unsigned b0 = (((unsigned)(m0 * 64 + cs_)) * 2u) ^ (((unsigned)m0 & 7u) << 4);
                unsigned b1x = (((unsigned)(m1 * 64 + cs_)) * 2u) ^ (((unsigned)m1 & 7u) << 4);
                *(u16*)((char*)h1 + b0) = f2bf(acc0[r] + bias2[hh * NTW + jl]);
                *(u16*)((char*)h1 + b1x) = f2bf(acc1[r] + bias2[hh * NTW + jl]);
            }
        }
        if constexpr (!DUAL) { if (hh + 1 < WH) __syncthreads(); }
    }

    // block-wide linear stream-out (row = relation-local message id)
    __syncthreads();                               // all col-slices staged
    const int mbase = tile * A;
    constexpr int CH = TILE * A * 16;              // uint2 chunks
#pragma unroll
    for (int i = 0; i < CH / 1024; ++i) {
        const int c    = i * 1024 + tid;
        const int row  = c >> 4;
        const int atom = row / A;
        if (tile + atom < T) {
            unsigned byte = (((unsigned)(row * 64 + (c & 15) * 4)) * 2u) ^ (((unsigned)row & 7u) << 4);
            uint2 v = *(const uint2*)((const char*)h1 + byte);
            *(uint2*)(msgR + (size_t)(mbase + row) * 64 + (c & 15) * 4) = v;
        }
    }
}

// ============ MEGA kernel: rank-atomic blocks striped 1-in-4 among msg blocks ============
struct MegaA {
    const u16* nsb;
    const int* idx0; const int* idx1; const int* idx2;
    int m0, m1, m2, t0, t1, t2;
    u32* cnt; u32* pre;
    const u16 *w10, *w20, *w11, *w21, *w12, *w22;
    const float *b10, *b20, *b11, *b21, *b12, *b22;
    u16* msgu;
    int nrank, nb2, nb1, nb0, striped;
};

__global__ __launch_bounds__(1024, 6) void mega_kernel(MegaA a) {
    __shared__ __align__(16) u16 sm[36864];        // 72KB
    const int bx = blockIdx.x;
    int kind, id;
    if (a.striped) {
        const int strip = 4 * a.nrank;
        if (bx < strip) {
            if ((bx & 3) == 3) { kind = 1; id = bx >> 2; }
            else               { kind = 0; id = bx - (bx >> 2); }
        } else { kind = 0; id = bx - a.nrank; }
    } else {
        if (bx < a.nrank) { kind = 1; id = bx; }
        else              { kind = 0; id = bx - a.nrank; }
    }

    if (kind == 1) {                               // pre-rank atomic pass
        const int Mtot = a.m0 + a.m1 + a.m2;
        for (int e = id * 1024 + (int)threadIdx.x; e < Mtot; e += a.nrank * 1024) {
            int lm = e, node;
            if (lm < a.m0) node = a.idx0[lm];
            else { lm -= a.m0; if (lm < a.m1) node = a.idx1[lm]; else node = a.idx2[lm - a.m1]; }
            a.pre[e] = atomicAdd(a.cnt + node, 1u);
        }
        return;
    }

    const int nmsg = a.nb2 + a.nb1 + a.nb0;
    if (id >= nmsg) return;
    if (id < a.nb2)
        msg_body<3>(a.nsb, a.idx2, a.w12, a.b12, a.w22, a.b22,
                    a.msgu + (size_t)(a.m0 + a.m1) * 64, a.t2, id, sm, sm + 12288);
    else if (id < a.nb2 + a.nb1)
        msg_body<2>(a.nsb, a.idx1, a.w11, a.b11, a.w21, a.b21,
                    a.msgu + (size_t)a.m0 * 64, a.t1, id - a.nb2, sm, sm + 16384);
    else
        msg_body<1>(a.nsb, a.idx0, a.w10, a.b10, a.w20, a.b20,
                    a.msgu, a.t0, id - a.nb2 - a.nb1, sm, sm + 8192);
}

// ================= fallback: fused with f32 atomics into d_out =================
template<int A>
__global__ __launch_bounds__(512) void rel_kernel(
    const float* __restrict__ ns, const int* __restrict__ idx,
    const u16* __restrict__ w1T, const float* __restrict__ b1,
    const u16* __restrict__ w2T, const float* __restrict__ b2,
    float* __restrict__ dout, int T)
{
    constexpr int D  = A * 64;
    constexpr int KS = D / 32;
    constexpr int NT = D / 16;
    constexpr bool DUAL = (A == 1);
    __shared__ __align__(16) u16 Wl[(DUAL ? 2 : 1) * D * D];
    __shared__ __align__(16) u16 h1[128 * D];

    const int tid  = threadIdx.x;
    const int lane = tid & 63;
    const int w    = tid >> 6;
    const int g    = lane >> 4;
    const int lr   = lane & 15;

    const int tile = blockIdx.x * 128;
    const int trow = tile + w * 16 + lr;
    const int tl   = trow < T ? trow : T - 1;

    {
        constexpr int NV = (DUAL ? 2 : 1) * D * D / 8;
        const uint4* s4 = (const uint4*)w1T;
        uint4* d4 = (uint4*)Wl;
#pragma unroll
        for (int i = 0; i < NV / 512; ++i) d4[i * 512 + tid] = s4[i * 512 + tid];
    }

    int nodes[A];
#pragma unroll
    for (int s = 0; s < A; ++s) nodes[s] = idx[(long)tl * A + s];

    bf16x8 a1[KS];
#pragma unroll
    for (int kk = 0; kk < KS; ++kk) {
        const float* p = ns + (long)nodes[kk >> 1] * H + ((kk & 1) * 32 + g * 8);
        float4 f0 = *(const float4*)p;
        float4 f1 = *(const float4*)(p + 4);
        F8 t;
        t.u[0] = f2bf(f0.x); t.u[1] = f2bf(f0.y); t.u[2] = f2bf(f0.z); t.u[3] = f2bf(f0.w);
        t.u[4] = f2bf(f1.x); t.u[5] = f2bf(f1.y); t.u[6] = f2bf(f1.z); t.u[7] = f2bf(f1.w);
        a1[kk] = t.b;
    }

    float bias1[NT];
#pragma unroll
    for (int j = 0; j < NT; ++j) bias1[j] = b1[j * 16 + lr];

    __syncthreads();

#pragma unroll
    for (int j = 0; j < NT; ++j) {
        f32x4 acc = {0.f, 0.f, 0.f, 0.f};
#pragma unroll
        for (int kk = 0; kk < KS; ++kk) {
            F8 bf; bf.q = *(const uint4*)((const char*)Wl + swz(j * 16 + lr, kk * 32 + g * 8, D));
            acc = __builtin_amdgcn_mfma_f32_16x16x32_bf16(a1[kk], bf.b, acc, 0, 0, 0);
        }
#pragma unroll
        for (int r = 0; r < 4; ++r) {
            float vv = acc[r] + bias1[j];
            vv = vv > 0.f ? vv : 0.f;
            int row = w * 16 + g * 4 + r;
            *(u16*)((char*)h1 + swz(row, j * 16 + lr, D)) = f2bf(vv);
        }
    }

    const char* W2base;
    if constexpr (!DUAL) {
        __syncthreads();
        const uint4* s4 = (const uint4*)w2T;
        uint4* d4 = (uint4*)Wl;
        constexpr int NV = D * D / 8;
#pragma unroll
        for (int i = 0; i < NV / 512; ++i) d4[i * 512 + tid] = s4[i * 512 + tid];
        W2base = (const char*)Wl;
    } else {
        W2base = (const char*)(Wl + D * D);
    }

    bf16x8 a2[KS];
#pragma unroll
    for (int kk = 0; kk < KS; ++kk) {
        int row = w * 16 + lr;
        F8 t; t.q = *(const uint4*)((const char*)h1 + swz(row, kk * 32 + g * 8, D));
        a2[kk] = t.b;
    }

    float bias2[NT];
#pragma unroll
    for (int j = 0; j < NT; ++j) bias2[j] = b2[j * 16 + lr];

    int  nodes2[A][4];
    bool pred[4];
#pragma unroll
    for (int r = 0; r < 4; ++r) {
        int t  = tile + w * 16 + g * 4 + r;
        int tc = t < T ? t : T - 1;
        pred[r] = t < T;
#pragma unroll
        for (int s = 0; s < A; ++s) nodes2[s][r] = idx[(long)tc * A + s];
    }
    if constexpr (!DUAL) __syncthreads();

#pragma unroll
    for (int j = 0; j < NT; ++j) {
        f32x4 acc = {0.f, 0.f, 0.f, 0.f};
#pragma unroll
        for (int kk = 0; kk < KS; ++kk) {
            F8 bf; bf.q = *(const uint4*)(W2base + swz(j * 16 + lr, kk * 32 + g * 8, D));
            acc = __builtin_amdgcn_mfma_f32_16x16x32_bf16(a2[kk], bf.b, acc, 0, 0, 0);
        }
        const int slot = j >> 2;
        const int coff = (j & 3) * 16 + lr;
#pragma unroll
        for (int r = 0; r < 4; ++r) {
            if (pred[r])
                unsafeAtomicAdd(dout + (long)nodes2[slot][r] * H + coff, acc[r] + bias2[j]);
        }
    }
}

// ---------------- update: fused segment-sum + 2-layer MLP ----------------
// MODE 0: SEG sequential (msgs sorted); MODE 1: SEG via ord; MODE 2: non-SEG.
template<int MODE>
__global__ __launch_bounds__(512) void update_kernel(
    const float* __restrict__ ns, const u16* __restrict__ nsb,
    const float* __restrict__ sum,
    const u32* __restrict__ ord, const u32* __restrict__ base,
    const u16* __restrict__ msg, int Mtot,
    const u16* __restrict__ wu1T, const float* __restrict__ bu1,
    const u16* __restrict__ wu2T, const float* __restrict__ bu2,
    float* __restrict__ out, int N)
{
    __shared__ __align__(16) u16 Wl[128 * 128 + 64 * 128];
    __shared__ __align__(16) u16 h[128 * 128];

    const int tid  = threadIdx.x;
    const int lane = tid & 63;
    const int w    = tid >> 6;
    const int g    = lane >> 4;
    const int lr   = lane & 15;

    {
        const uint4* s4 = (const uint4*)wu1T;
        uint4* d4 = (uint4*)Wl;
#pragma unroll
        for (int i = 0; i < 6; ++i) d4[i * 512 + tid] = s4[i * 512 + tid];
    }

    const int tile = blockIdx.x * 128;
    const int trow = tile + w * 16 + lr;
    const int tl   = trow < N ? trow : N - 1;

    bf16x8 a1[4];
    if constexpr (MODE <= 1) {
        const u32 s = base[tl];
        const u32 e = (tl + 1 < N) ? base[tl + 1] : (u32)Mtot;
        float s0[8], s1[8];
#pragma unroll
        for (int j = 0; j < 8; ++j) { s0[j] = 0.f; s1[j] = 0.f; }
        for (u32 p = s; p < e; ++p) {
            const u16* row = msg + (size_t)(MODE == 1 ? ord[p] : p) * 64;
            F8 v0, v1;
            v0.q = *(const uint4*)(row + g * 8);
            v1.q = *(const uint4*)(row + 32 + g * 8);
#pragma unroll
            for (int j = 0; j < 8; ++j) { s0[j] += bf2f(v0.u[j]); s1[j] += bf2f(v1.u[j]); }
        }
        F8 t0, t1;
#pragma unroll
        for (int j = 0; j < 8; ++j) { t0.u[j] = f2bf(s0[j]); t1.u[j] = f2bf(s1[j]); }
        a1[0] = t0.b; a1[1] = t1.b;
    } else {
#pragma unroll
        for (int kk = 0; kk < 2; ++kk) {
            int k = kk * 32 + g * 8;
            const float* p = sum + (long)tl * H + k;
            float4 f0 = *(const float4*)p;
            float4 f1 = *(const float4*)(p + 4);
            F8 t;
            t.u[0] = f2bf(f0.x); t.u[1] = f2bf(f0.y); t.u[2] = f2bf(f0.z); t.u[3] = f2bf(f0.w);
            t.u[4] = f2bf(f1.x); t.u[5] = f2bf(f1.y); t.u[6] = f2bf(f1.z); t.u[7] = f2bf(f1.w);
            a1[kk] = t.b;
        }
    }
#pragma unroll
    for (int kk = 2; kk < 4; ++kk) {
        if constexpr (MODE <= 1) {
            const u16* prow = nsb + (long)tl * H;
            F8 t; t.q = *(const uint4*)(prow + (kk - 2) * 32 + g * 8);
            a1[kk] = t.b;
        } else {
            int k = (kk - 2) * 32 + g * 8;
            const float* p = ns + (long)tl * H + k;
            float4 f0 = *(const float4*)p;
            float4 f1 = *(const float4*)(p + 4);
            F8 t;
            t.u[0] = f2bf(f0.x); t.u[1] = f2bf(f0.y); t.u[2] = f2bf(f0.z); t.u[3] = f2bf(f0.w);
            t.u[4] = f2bf(f1.x); t.u[5] = f2bf(f1.y); t.u[6] = f2bf(f1.z); t.u[7] = f2bf(f1.w);
            a1[kk] = t.b;
        }
    }

    float bias1[8], bias2[4];
#pragma unroll
    for (int j = 0; j < 8; ++j) bias1[j] = bu1[j * 16 + lr];
#pragma unroll
    for (int j = 0; j < 4; ++j) bias2[j] = bu2[j * 16 + lr];

    __syncthreads();

#pragma unroll
    for (int j = 0; j < 8; ++j) {
        f32x4 acc = {0.f, 0.f, 0.f, 0.f};
#pragma unroll
        for (int kk = 0; kk < 4; ++kk) {
            F8 bf; bf.q = *(const uint4*)((const char*)Wl + swz(j * 16 + lr, kk * 32 + g * 8, 128));
            acc = __builtin_amdgcn_mfma_f32_16x16x32_bf16(a1[kk], bf.b, acc, 0, 0, 0);
        }
#pragma unroll
        for (int r = 0; r < 4; ++r) {
            float vv = acc[r] + bias1[j];
            vv = vv > 0.f ? vv : 0.f;
            int row = w * 16 + g * 4 + r;
            *(u16*)((char*)h + swz(row, j * 16 + lr, 128)) = f2bf(vv);
        }
    }

    bf16x8 a2[4];
#pragma unroll
    for (int kk = 0; kk < 4; ++kk) {
        int row = w * 16 + lr;
        F8 t; t.q = *(const uint4*)((const char*)h + swz(row, kk * 32 + g * 8, 128));
        a2[kk] = t.b;
    }

    const char* W2base = (const char*)(Wl + 128 * 128);
#pragma unroll
    for (int j = 0; j < 4; ++j) {
        f32x4 acc = {0.f, 0.f, 0.f, 0.f};
#pragma unroll
        for (int kk = 0; kk < 4; ++kk) {
            F8 bf; bf.q = *(const uint4*)(W2base + swz(j * 16 + lr, kk * 32 + g * 8, 128));
            acc = __builtin_amdgcn_mfma_f32_16x16x32_bf16(a2[kk], bf.b, acc, 0, 0, 0);
        }
#pragma unroll
        for (int r = 0; r < 4; ++r) {
            int t = tile + w * 16 + g * 4 + r;
            if (t < N) out[(long)t * H + j * 16 + lr] = acc[r] + bias2[j];
        }
    }
}

// ---------------- launcher ----------------
extern "C" void kernel_launch(void* const* d_in, const int* in_sizes, int n_in,
                              void* d_out, int out_size, void* d_ws, size_t ws_size,
                              hipStream_t stream) {
    const float* ns = (const float*)d_in[0];
    const int* idxs[3] = { (const int*)d_in[1], (const int*)d_in[6], (const int*)d_in[11] };
    const float* b1s[3] = { (const float*)d_in[3], (const float*)d_in[8], (const float*)d_in[13] };
    const float* b2s[3] = { (const float*)d_in[5], (const float*)d_in[10], (const float*)d_in[15] };
    const float* bu1 = (const float*)d_in[17];
    const float* bu2 = (const float*)d_in[19];

    const int N = in_sizes[0] / H;
    const int Ts[3] = { in_sizes[1], in_sizes[6] / 2, in_sizes[11] / 3 };
    const int Ms[3] = { Ts[0] * 1, Ts[1] * 2, Ts[2] * 3 };
    const long Mtot = (long)Ms[0] + Ms[1] + Ms[2];

    char* wsb = (char*)d_ws;
    auto AL = [](size_t x) { return (x + 255) & ~(size_t)255; };

    const unsigned O_W1R0 = 0;
    const unsigned O_W2R0 = O_W1R0 + 64 * 64 * 2;
    const unsigned O_W1R1 = O_W2R0 + 64 * 64 * 2;
    const unsigned O_W2R1 = O_W1R1 + 128 * 128 * 2;
    const unsigned O_W1R2 = O_W2R1 + 128 * 128 * 2;
    const unsigned O_W2R2 = O_W1R2 + 192 * 192 * 2;
    const unsigned O_WU1  = O_W2R2 + 192 * 192 * 2;
    const unsigned O_WU2  = O_WU1 + 128 * 128 * 2;
    const size_t  wEnd    = O_WU2 + 128 * 64 * 2;
    const unsigned wOff1[3] = { O_W1R0, O_W1R1, O_W1R2 };
    const unsigned wOff2[3] = { O_W2R0, O_W2R1, O_W2R2 };

    const int nb = (N + 511) / 512;

    const size_t O_CNT = AL(wEnd);                       // counts -> base after scan
    const size_t O_SUM = AL(O_CNT + (size_t)N * 4);
    const size_t O_PRE = AL(O_SUM + (size_t)nb * 4);
    const size_t O_ORD = AL(O_PRE + (size_t)Mtot * 4);
    const size_t O_NSB = AL(O_ORD + (size_t)Mtot * 4);
    const size_t nsLen = (size_t)N * H * 2;
    const size_t O_MSG = AL(O_NSB + nsLen);
    const size_t O_MSGS = AL(O_MSG + (size_t)Mtot * 128);
    const size_t need1 = O_MSGS;                          // ord path
    const size_t need2 = O_MSGS + (size_t)Mtot * 128;     // scatter path

    const bool sorted2 = (nb <= 512) && (ws_size >= need2);
    const bool sorted1 = (nb <= 512) && (ws_size >= need1);

    Segs segs;
    segs.s[0] = {(const float*)d_in[2],  O_W1R0, 64, 64};
    segs.s[1] = {(const float*)d_in[4],  O_W2R0, 64, 64};
    segs.s[2] = {(const float*)d_in[7],  O_W1R1, 128, 128};
    segs.s[3] = {(const float*)d_in[9],  O_W2R1, 128, 128};
    segs.s[4] = {(const float*)d_in[12], O_W1R2, 192, 192};
    segs.s[5] = {(const float*)d_in[14], O_W2R2, 192, 192};
    segs.s[6] = {(const float*)d_in[16], O_WU1, 128, 128};
    segs.s[7] = {(const float*)d_in[18], O_WU2, 128, 64};

    float* dout = (float*)d_out;
    const u16* W1[3] = { (const u16*)(wsb + wOff1[0]), (const u16*)(wsb + wOff1[1]), (const u16*)(wsb + wOff1[2]) };
    const u16* W2[3] = { (const u16*)(wsb + wOff2[0]), (const u16*)(wsb + wOff2[1]), (const u16*)(wsb + wOff2[2]) };

    auto gT = [](int T) { return (T + 127) / 128; };

    if (sorted1 || sorted2) {
        u32* cnt = (u32*)(wsb + O_CNT);
        u32* sums = (u32*)(wsb + O_SUM);
        u32* pre = (u32*)(wsb + O_PRE);
        u32* ord = (u32*)(wsb + O_ORD);
        u16* nsbp = (u16*)(wsb + O_NSB);
        u16* msgu = (u16*)(wsb + O_MSG);
        u16* msgs = (u16*)(wsb + O_MSGS);

        PrepA pp;
        pp.nsrc = (const float4*)ns; pp.ndst = (ushort4*)nsbp; pp.n4 = N * H / 4;
        pp.segs = segs; pp.wout = wsb; pp.cnt = cnt; pp.N = N;
        prep_kernel<<<dim3(448, 3), 256, 0, stream>>>(pp);

        const int nb0 = (Ts[0] + 255) / 256;   // A=1 uses 256-atom tiles now
        const int nb1 = gT(Ts[1]), nb2 = gT(Ts[2]);
        const int nmsg = nb0 + nb1 + nb2;
        int NR = nmsg / 3; if (NR > 1024) NR = 1024; if (NR < 1) NR = 1;
        const int striped = (nmsg >= 3 * NR) ? 1 : 0;
        const int NTOT = NR + nmsg;

        MegaA ma;
        ma.nsb = nsbp;
        ma.idx0 = idxs[0]; ma.idx1 = idxs[1]; ma.idx2 = idxs[2];
        ma.m0 = Ms[0]; ma.m1 = Ms[1]; ma.m2 = Ms[2];
        ma.t0 = Ts[0]; ma.t1 = Ts[1]; ma.t2 = Ts[2];
        ma.cnt = cnt; ma.pre = pre;
        ma.w10 = W1[0]; ma.w20 = W2[0];
        ma.w11 = W1[1]; ma.w21 = W2[1];
        ma.w12 = W1[2]; ma.w22 = W2[2];
        ma.b10 = b1s[0]; ma.b20 = b2s[0];
        ma.b11 = b1s[1]; ma.b21 = b2s[1];
        ma.b12 = b1s[2]; ma.b22 = b2s[2];
        ma.msgu = msgu;
        ma.nrank = NR; ma.nb2 = nb2; ma.nb1 = nb1; ma.nb0 = nb0; ma.striped = striped;
        mega_kernel<<<NTOT, 1024, 0, stream>>>(ma);

        scan_blocks<<<nb, 512, 0, stream>>>(cnt, sums, N);
        scan_sums<<<1, 512, 0, stream>>>(sums, nb);
        scan_add<<<nb, 512, 0, stream>>>(cnt, sums, N);

        if (sorted2) {
            Scat sc;
            sc.idx0 = idxs[0]; sc.idx1 = idxs[1]; sc.idx2 = idxs[2];
            sc.m0 = Ms[0]; sc.m1 = Ms[1]; sc.m2 = Ms[2];
            sc.base = cnt; sc.pre = pre;
            sc.msgu = msgu; sc.msgs = msgs;
            scatter_msg<<<2048, 256, 0, stream>>>(sc);

            update_kernel<0><<<(N + 127) / 128, 512, 0, stream>>>(
                ns, nsbp, nullptr, nullptr, cnt, msgs, (int)Mtot,
                (const u16*)(wsb + O_WU1), bu1, (const u16*)(wsb + O_WU2), bu2, dout, N);
        } else {
            OFix fx;
            fx.idx0 = idxs[0]; fx.idx1 = idxs[1]; fx.idx2 = idxs[2];
            fx.m0 = Ms[0]; fx.m1 = Ms[1]; fx.m2 = Ms[2];
            fx.base = cnt; fx.pre = pre; fx.ord = ord;
            ord_fix<<<2048, 256, 0, stream>>>(fx);

            update_kernel<1><<<(N + 127) / 128, 512, 0, stream>>>(
                ns, nsbp, nullptr, ord, cnt, msgu, (int)Mtot,
                (const u16*)(wsb + O_WU1), bu1, (const u16*)(wsb + O_WU2), bu2, dout, N);
        }
    } else {
        conv_weights<<<dim3(36, 8), 256, 0, stream>>>(segs, wsb);
        hipMemsetAsync(dout, 0, (size_t)N * H * sizeof(float), stream);
        for (int r = 0; r < 3; ++r) {
            const int T = Ts[r], nbl = gT(T);
            if (r == 0) rel_kernel<1><<<nbl, 512, 0, stream>>>(ns, idxs[0], W1[0], b1s[0], W2[0], b2s[0], dout, T);
            if (r == 1) rel_kernel<2><<<nbl, 512, 0, stream>>>(ns, idxs[1], W1[1], b1s[1], W2[1], b2s[1], dout, T);
            if (r == 2) rel_kernel<3><<<nbl, 512, 0, stream>>>(ns, idxs[2], W1[2], b1s[2], W2[2], b2s[2], dout, T);
        }
        update_kernel<2><<<(N + 127) / 128, 512, 0, stream>>>(
            ns, nullptr, dout, nullptr, nullptr, nullptr, 0,
            (const u16*)(wsb + O_WU1), bu1, (const u16*)(wsb + O_WU2), bu2, dout, N);
    }
}

// Round 13
// 266.341 us; speedup vs baseline: 1.5795x; 1.5795x over previous
//
#include <hip/hip_runtime.h>

#define H 64

typedef __attribute__((ext_vector_type(8))) __bf16 bf16x8;
typedef __attribute__((ext_vector_type(4))) float f32x4;
typedef unsigned short u16;
typedef unsigned int u32;

union F8 { bf16x8 b; u16 u[8]; uint4 q; };

// Hardware bf16 convert (v_cvt on gfx950; RNE).
__device__ __forceinline__ u16 f2bf(float f) {
    union { __bf16 h; u16 u; } v; v.h = (__bf16)f; return v.u;
}
__device__ __forceinline__ float bf2f(u16 x) {
    return __uint_as_float((u32)x << 16);
}
// Swizzled layout: element (col,k) at byte ((col*K+k)*2) ^ ((col&7)<<4).
__device__ __forceinline__ unsigned swz(int col, int k, int K) {
    return ((unsigned)(col * K + k) * 2u) ^ (((unsigned)col & 7u) << 4);
}

// ---------------- weight convert (fallback path) ----------------
struct Seg { const float* src; unsigned dstBytes; int K; int N; };
struct Segs { Seg s[8]; };

__global__ __launch_bounds__(256) void conv_weights(Segs segs, char* out) {
    Seg sg = segs.s[blockIdx.y];
    int total = sg.K * sg.N;
    char* dst = out + sg.dstBytes;
    for (int e = blockIdx.x * 256 + threadIdx.x; e < total; e += gridDim.x * 256) {
        int k = e / sg.N, n = e % sg.N;
        *(u16*)(dst + swz(n, k, sg.K)) = f2bf(sg.src[e]);
    }
}

// ---- prep: fused node convert + weight convert + cnt zero (1 launch) ----
struct PrepA { const float4* nsrc; ushort4* ndst; int n4; Segs segs; char* wout; u32* cnt; int N; };

__global__ __launch_bounds__(256) void prep_kernel(PrepA a) {
    if (blockIdx.y == 0) {
        for (int i = blockIdx.x * 256 + threadIdx.x; i < a.n4; i += gridDim.x * 256) {
            float4 f = a.nsrc[i];
            ushort4 o;
            o.x = f2bf(f.x); o.y = f2bf(f.y); o.z = f2bf(f.z); o.w = f2bf(f.w);
            a.ndst[i] = o;
        }
    } else if (blockIdx.y == 1) {
        for (int s = 0; s < 8; ++s) {
            Seg sg = a.segs.s[s];
            int total = sg.K * sg.N;
            char* dst = a.wout + sg.dstBytes;
            for (int e = blockIdx.x * 256 + threadIdx.x; e < total; e += gridDim.x * 256) {
                int k = e / sg.N, n = e % sg.N;
                *(u16*)(dst + swz(n, k, sg.K)) = f2bf(sg.src[e]);
            }
        }
    } else {
        for (int i = blockIdx.x * 256 + threadIdx.x; i < a.N; i += gridDim.x * 256)
            a.cnt[i] = 0u;
    }
}

// ---------------- scan (2 kernels; R26: scan_add folded into consumers) ----------------
__global__ __launch_bounds__(512) void scan_blocks(u32* __restrict__ data,
                                                   u32* __restrict__ sums, int n) {
    __shared__ u32 s[512];
    int tid = threadIdx.x, i = blockIdx.x * 512 + tid;
    u32 v = (i < n) ? data[i] : 0u;
    s[tid] = v; __syncthreads();
    for (int d = 1; d < 512; d <<= 1) {
        u32 t = (tid >= d) ? s[tid - d] : 0u; __syncthreads();
        s[tid] += t; __syncthreads();
    }
    if (i < n) data[i] = s[tid] - v;               // exclusive (intra-block)
    if (tid == 511) sums[blockIdx.x] = s[511];
}

__global__ __launch_bounds__(512) void scan_sums(u32* __restrict__ sums, int nb) {
    __shared__ u32 s[512];
    int tid = threadIdx.x;
    u32 v = (tid < nb) ? sums[tid] : 0u;
    s[tid] = v; __syncthreads();
    for (int d = 1; d < 512; d <<= 1) {
        u32 t = (tid >= d) ? s[tid - d] : 0u; __syncthreads();
        s[tid] += t; __syncthreads();
    }
    if (tid < nb) sums[tid] = s[tid] - v;          // exclusive
}

// ---- ord scatter (fallback path): ord[base(node) + pre[m]] = m ----
// base(t) = cnt[t] + sums[t>>9]  (sums is L1-resident; saves the scan_add pass)
struct OFix {
    const int* idx0; const int* idx1; const int* idx2;
    int m0, m1, m2;
    const u32* base; const u32* sums; const u32* pre; u32* ord;
};

__global__ __launch_bounds__(256) void ord_fix(OFix a) {
    const int Mtot = a.m0 + a.m1 + a.m2;
    for (int e = blockIdx.x * 256 + threadIdx.x; e < Mtot; e += gridDim.x * 256) {
        int lm = e, node;
        if (lm < a.m0) node = a.idx0[lm];
        else { lm -= a.m0; if (lm < a.m1) node = a.idx1[lm]; else node = a.idx2[lm - a.m1]; }
        a.ord[a.base[node] + a.sums[node >> 9] + a.pre[e]] = (u32)e;
    }
}

// ---- message permute: msgs[base(node)+pre[e]] = msgu[e] ----
struct Scat {
    const int* idx0; const int* idx1; const int* idx2;
    int m0, m1, m2;
    const u32* base; const u32* sums; const u32* pre;
    const u16* msgu; u16* msgs;
};

__global__ __launch_bounds__(256) void scatter_msg(Scat a) {
    const int Mtot = a.m0 + a.m1 + a.m2;
    const int CH = Mtot * 8;                       // 16B chunks
    for (int c = blockIdx.x * 256 + threadIdx.x; c < CH; c += gridDim.x * 256) {
        const int e = c >> 3, q = c & 7;
        int lm = e, node;
        if (lm < a.m0) node = a.idx0[lm];
        else { lm -= a.m0; if (lm < a.m1) node = a.idx1[lm]; else node = a.idx2[lm - a.m1]; }
        const u32 slot = a.base[node] + a.sums[node >> 9] + a.pre[e];
        ((uint4*)(a.msgs + (size_t)slot * 64))[q] =
            ((const uint4*)(a.msgu + (size_t)e * 64))[q];
    }
}

// ============ msg body: fused 2-layer MLP -> UNSORTED msg rows ============
// R24 PROVEN structure (R14/R17/R23/R25 all spilled when per-thread state or
// block shape changed — do not revisit): 512 threads, col-split 2-way for
// A>=2 (wave = 32 rows x half cols); DMA staging; bf16 nsb gather.
// R26: s_setprio(1) around MFMA clusters — mega co-schedules MFMA (msg) and
// atomic (rank) blocks per CU; different-phase wave mix is where setprio
// measured positive (m191), unlike lockstep GEMM (m190 null).
template<int A>
__device__ __forceinline__ void msg_body(
    const u16* __restrict__ nsb, const int* __restrict__ idx,
    const u16* __restrict__ w1T, const float* __restrict__ b1,
    const u16* __restrict__ w2T, const float* __restrict__ b2,
    u16* __restrict__ msgR, int T, int bid, u16* Wl, u16* h1)
{
    constexpr int D    = A * 64;
    constexpr int KS   = D / 32;
    constexpr int NT   = D / 16;
    constexpr bool DUAL = (A == 1);
    constexpr bool CS   = (A > 1);          // col-split 2-way
    constexpr int RF   = CS ? 2 : 1;        // row fragments per wave
    constexpr int WH   = (A == 3) ? 3 : 1;  // W column-chunks
    constexpr int NTH  = NT / WH;           // col tiles per chunk
    constexpr int NTW  = CS ? NTH / 2 : NTH;// col tiles per wave per chunk
    constexpr int COLH = D / WH;
    constexpr int NPF  = (DUAL ? 2 * D * D : COLH * D) / 8 / 512;
    constexpr int NB   = WH * NTW;          // bias entries per wave

    const int tid  = threadIdx.x;
    const int lane = tid & 63;
    const int w    = tid >> 6;
    const int g    = lane >> 4;
    const int lr   = lane & 15;
    const int rg   = CS ? (w >> 1) : w;     // row group
    const int cg   = CS ? (w & 1) : 0;      // col half

    const int tile = bid * 128;

    auto stage = [&](const u16* gsrc) {
#pragma unroll
        for (int i = 0; i < NPF; ++i) {
            const u16* gp = gsrc + ((i * 512 + tid) << 3);
            u16* lp = Wl + ((i * 512 + (w << 6)) << 3);
            __builtin_amdgcn_global_load_lds(
                (const __attribute__((address_space(1))) void*)gp,
                (__attribute__((address_space(3))) void*)lp, 16, 0, 0);
        }
    };

    // A-fragment gather (bf16), RF row-frags per wave
    bf16x8 a1[RF][KS];
#pragma unroll
    for (int rf = 0; rf < RF; ++rf) {
        const int trow = tile + rg * (16 * RF) + rf * 16 + lr;
        const int tl   = trow < T ? trow : T - 1;
        int nodes[A];
#pragma unroll
        for (int s = 0; s < A; ++s) nodes[s] = idx[(long)tl * A + s];
#pragma unroll
        for (int kk = 0; kk < KS; ++kk) {
            const u16* p = nsb + (long)nodes[kk >> 1] * H + ((kk & 1) * 32 + g * 8);
            F8 t; t.q = *(const uint4*)p;
            a1[rf][kk] = t.b;
        }
    }

    float bias1[NB], bias2[NB];
#pragma unroll
    for (int i = 0; i < NB; ++i) {
        const int jg = (i / NTW) * NTH + cg * NTW + (i % NTW);
        bias1[i] = b1[jg * 16 + lr];
        bias2[i] = b2[jg * 16 + lr];
    }

    // ---- GEMM1 over W1 column-chunks ----
#pragma unroll
    for (int hh = 0; hh < WH; ++hh) {
        stage(DUAL ? w1T : (w1T + (size_t)hh * COLH * D));
        asm volatile("s_waitcnt vmcnt(0)" ::: "memory");
        __syncthreads();

#pragma unroll
        for (int jl = 0; jl < NTW; ++jl) {
            const int jc = cg * NTW + jl;          // col tile within chunk
            const int jg = hh * NTH + jc;
            f32x4 acc0 = {0.f, 0.f, 0.f, 0.f};
            f32x4 acc1 = {0.f, 0.f, 0.f, 0.f};
            __builtin_amdgcn_s_setprio(1);
#pragma unroll
            for (int kk = 0; kk < KS; ++kk) {
                F8 bf; bf.q = *(const uint4*)((const char*)Wl + swz(jc * 16 + lr, kk * 32 + g * 8, D));
                acc0 = __builtin_amdgcn_mfma_f32_16x16x32_bf16(a1[0][kk], bf.b, acc0, 0, 0, 0);
                if constexpr (CS)
                    acc1 = __builtin_amdgcn_mfma_f32_16x16x32_bf16(a1[1][kk], bf.b, acc1, 0, 0, 0);
            }
            __builtin_amdgcn_s_setprio(0);
#pragma unroll
            for (int r = 0; r < 4; ++r) {
                const int row0 = rg * (16 * RF) + g * 4 + r;
                float v0 = acc0[r] + bias1[hh * NTW + jl]; v0 = v0 > 0.f ? v0 : 0.f;
                *(u16*)((char*)h1 + swz(row0, jg * 16 + lr, D)) = f2bf(v0);
                if constexpr (CS) {
                    float v1 = acc1[r] + bias1[hh * NTW + jl]; v1 = v1 > 0.f ? v1 : 0.f;
                    *(u16*)((char*)h1 + swz(row0 + 16, jg * 16 + lr, D)) = f2bf(v1);
                }
            }
        }
        if constexpr (!DUAL) __syncthreads();      // all h1 chunk-writes visible
    }

    // a2 fragments: wave's RF*16 h1 rows, full D
    bf16x8 a2[RF][KS];
#pragma unroll
    for (int rf = 0; rf < RF; ++rf) {
        const int row = rg * (16 * RF) + rf * 16 + lr;
#pragma unroll
        for (int kk = 0; kk < KS; ++kk) {
            F8 t; t.q = *(const uint4*)((const char*)h1 + swz(row, kk * 32 + g * 8, D));
            a2[rf][kk] = t.b;
        }
    }

    // ---- GEMM2 over W2 column-chunks -> stage msg rows into h1 region ----
#pragma unroll
    for (int hh = 0; hh < WH; ++hh) {
        if constexpr (!DUAL) {
            stage(w2T + (size_t)hh * COLH * D);
            asm volatile("s_waitcnt vmcnt(0)" ::: "memory");
            __syncthreads();
        }
        const char* W2base = DUAL ? (const char*)(Wl + D * D) : (const char*)Wl;

#pragma unroll
        for (int jl = 0; jl < NTW; ++jl) {
            const int jc = cg * NTW + jl;
            const int jg = hh * NTH + jc;
            f32x4 acc0 = {0.f, 0.f, 0.f, 0.f};
            f32x4 acc1 = {0.f, 0.f, 0.f, 0.f};
            __builtin_amdgcn_s_setprio(1);
#pragma unroll
            for (int kk = 0; kk < KS; ++kk) {
                F8 bf; bf.q = *(const uint4*)(W2base + swz(jc * 16 + lr, kk * 32 + g * 8, D));
                acc0 = __builtin_amdgcn_mfma_f32_16x16x32_bf16(a2[0][kk], bf.b, acc0, 0, 0, 0);
                if constexpr (CS)
                    acc1 = __builtin_amdgcn_mfma_f32_16x16x32_bf16(a2[1][kk], bf.b, acc1, 0, 0, 0);
            }
            __builtin_amdgcn_s_setprio(0);
            const int gc   = jg * 16 + lr;
            const int slot = gc >> 6;
            const int cs_  = gc & 63;
#pragma unroll
            for (int r = 0; r < 4; ++r) {
                const int a0 = rg * (16 * RF) + g * 4 + r;
                const int m0 = a0 * A + slot;
                unsigned b0 = (((unsigned)(m0 * 64 + cs_)) * 2u) ^ (((unsigned)m0 & 7u) << 4);
                *(u16*)((char*)h1 + b0) = f2bf(acc0[r] + bias2[hh * NTW + jl]);
                if constexpr (CS) {
                    const int m1 = (a0 + 16) * A + slot;
                    unsigned b1x = (((unsigned)(m1 * 64 + cs_)) * 2u) ^ (((unsigned)m1 & 7u) << 4);
                    *(u16*)((char*)h1 + b1x) = f2bf(acc1[r] + bias2[hh * NTW + jl]);
                }
            }
        }
        if constexpr (!DUAL) { if (hh + 1 < WH) __syncthreads(); }
    }

    // linear stream-out (row = relation-local message id; fully coalesced)
    if constexpr (CS) {
        __syncthreads();                           // partner col-halves staged
        const int mbase = tile * A;
        constexpr int CH = 128 * A * 16;           // uint2 chunks
#pragma unroll
        for (int i = 0; i < CH / 512; ++i) {
            const int c    = i * 512 + tid;
            const int row  = c >> 4;
            const int atom = row / A;
            if (tile + atom < T) {
                unsigned byte = (((unsigned)(row * 64 + (c & 15) * 4)) * 2u) ^ (((unsigned)row & 7u) << 4);
                uint2 v = *(const uint2*)((const char*)h1 + byte);
                *(uint2*)(msgR + (size_t)(mbase + row) * 64 + (c & 15) * 4) = v;
            }
        }
    } else {
        const bool full  = (tile + 128 <= T);
#pragma unroll
        for (int i = 0; i < 16 * A; i += 4) {
            int ml   = i + (lane >> 4);
            int mrow = w * 16 * A + ml;
            bool ok  = full || ((tile + w * 16 + ml / A) < T);
            if (ok) {
                unsigned byte = (((unsigned)(mrow * 64 + (lane & 15) * 4)) * 2u) ^ (((unsigned)mrow & 7u) << 4);
                uint2 v = *(const uint2*)((const char*)h1 + byte);
                *(uint2*)(msgR + (size_t)((tile * A) + mrow) * 64 + (lane & 15) * 4) = v;
            }
        }
    }
}

// ============ MEGA kernel: rank-atomic blocks striped 1-in-4 among msg blocks ============
struct MegaA {
    const u16* nsb;
    const int* idx0; const int* idx1; const int* idx2;
    int m0, m1, m2, t0, t1, t2;
    u32* cnt; u32* pre;
    const u16 *w10, *w20, *w11, *w21, *w12, *w22;
    const float *b10, *b20, *b11, *b21, *b12, *b22;
    u16* msgu;
    int nrank, nb2, nb1, nb0, striped;
};

__global__ __launch_bounds__(512, 4) void mega_kernel(MegaA a) {
    __shared__ __align__(16) u16 sm[36864];        // 72KB
    const int bx = blockIdx.x;
    int kind, id;
    if (a.striped) {
        const int strip = 4 * a.nrank;
        if (bx < strip) {
            if ((bx & 3) == 3) { kind = 1; id = bx >> 2; }
            else               { kind = 0; id = bx - (bx >> 2); }
        } else { kind = 0; id = bx - a.nrank; }
    } else {
        if (bx < a.nrank) { kind = 1; id = bx; }
        else              { kind = 0; id = bx - a.nrank; }
    }

    if (kind == 1) {                               // pre-rank atomic pass
        const int Mtot = a.m0 + a.m1 + a.m2;
        for (int e = id * 512 + (int)threadIdx.x; e < Mtot; e += a.nrank * 512) {
            int lm = e, node;
            if (lm < a.m0) node = a.idx0[lm];
            else { lm -= a.m0; if (lm < a.m1) node = a.idx1[lm]; else node = a.idx2[lm - a.m1]; }
            a.pre[e] = atomicAdd(a.cnt + node, 1u);
        }
        return;
    }

    const int nmsg = a.nb2 + a.nb1 + a.nb0;
    if (id >= nmsg) return;
    if (id < a.nb2)
        msg_body<3>(a.nsb, a.idx2, a.w12, a.b12, a.w22, a.b22,
                    a.msgu + (size_t)(a.m0 + a.m1) * 64, a.t2, id, sm, sm + 12288);
    else if (id < a.nb2 + a.nb1)
        msg_body<2>(a.nsb, a.idx1, a.w11, a.b11, a.w21, a.b21,
                    a.msgu + (size_t)a.m0 * 64, a.t1, id - a.nb2, sm, sm + 16384);
    else
        msg_body<1>(a.nsb, a.idx0, a.w10, a.b10, a.w20, a.b20,
                    a.msgu, a.t0, id - a.nb2 - a.nb1, sm, sm + 8192);
}

// ================= fallback: fused with f32 atomics into d_out =================
template<int A>
__global__ __launch_bounds__(512) void rel_kernel(
    const float* __restrict__ ns, const int* __restrict__ idx,
    const u16* __restrict__ w1T, const float* __restrict__ b1,
    const u16* __restrict__ w2T, const float* __restrict__ b2,
    float* __restrict__ dout, int T)
{
    constexpr int D  = A * 64;
    constexpr int KS = D / 32;
    constexpr int NT = D / 16;
    constexpr bool DUAL = (A == 1);
    __shared__ __align__(16) u16 Wl[(DUAL ? 2 : 1) * D * D];
    __shared__ __align__(16) u16 h1[128 * D];

    const int tid  = threadIdx.x;
    const int lane = tid & 63;
    const int w    = tid >> 6;
    const int g    = lane >> 4;
    const int lr   = lane & 15;

    const int tile = blockIdx.x * 128;
    const int trow = tile + w * 16 + lr;
    const int tl   = trow < T ? trow : T - 1;

    {
        constexpr int NV = (DUAL ? 2 : 1) * D * D / 8;
        const uint4* s4 = (const uint4*)w1T;
        uint4* d4 = (uint4*)Wl;
#pragma unroll
        for (int i = 0; i < NV / 512; ++i) d4[i * 512 + tid] = s4[i * 512 + tid];
    }

    int nodes[A];
#pragma unroll
    for (int s = 0; s < A; ++s) nodes[s] = idx[(long)tl * A + s];

    bf16x8 a1[KS];
#pragma unroll
    for (int kk = 0; kk < KS; ++kk) {
        const float* p = ns + (long)nodes[kk >> 1] * H + ((kk & 1) * 32 + g * 8);
        float4 f0 = *(const float4*)p;
        float4 f1 = *(const float4*)(p + 4);
        F8 t;
        t.u[0] = f2bf(f0.x); t.u[1] = f2bf(f0.y); t.u[2] = f2bf(f0.z); t.u[3] = f2bf(f0.w);
        t.u[4] = f2bf(f1.x); t.u[5] = f2bf(f1.y); t.u[6] = f2bf(f1.z); t.u[7] = f2bf(f1.w);
        a1[kk] = t.b;
    }

    float bias1[NT];
#pragma unroll
    for (int j = 0; j < NT; ++j) bias1[j] = b1[j * 16 + lr];

    __syncthreads();

#pragma unroll
    for (int j = 0; j < NT; ++j) {
        f32x4 acc = {0.f, 0.f, 0.f, 0.f};
#pragma unroll
        for (int kk = 0; kk < KS; ++kk) {
            F8 bf; bf.q = *(const uint4*)((const char*)Wl + swz(j * 16 + lr, kk * 32 + g * 8, D));
            acc = __builtin_amdgcn_mfma_f32_16x16x32_bf16(a1[kk], bf.b, acc, 0, 0, 0);
        }
#pragma unroll
        for (int r = 0; r < 4; ++r) {
            float vv = acc[r] + bias1[j];
            vv = vv > 0.f ? vv : 0.f;
            int row = w * 16 + g * 4 + r;
            *(u16*)((char*)h1 + swz(row, j * 16 + lr, D)) = f2bf(vv);
        }
    }

    const char* W2base;
    if constexpr (!DUAL) {
        __syncthreads();
        const uint4* s4 = (const uint4*)w2T;
        uint4* d4 = (uint4*)Wl;
        constexpr int NV = D * D / 8;
#pragma unroll
        for (int i = 0; i < NV / 512; ++i) d4[i * 512 + tid] = s4[i * 512 + tid];
        W2base = (const char*)Wl;
    } else {
        W2base = (const char*)(Wl + D * D);
    }

    bf16x8 a2[KS];
#pragma unroll
    for (int kk = 0; kk < KS; ++kk) {
        int row = w * 16 + lr;
        F8 t; t.q = *(const uint4*)((const char*)h1 + swz(row, kk * 32 + g * 8, D));
        a2[kk] = t.b;
    }

    float bias2[NT];
#pragma unroll
    for (int j = 0; j < NT; ++j) bias2[j] = b2[j * 16 + lr];

    int  nodes2[A][4];
    bool pred[4];
#pragma unroll
    for (int r = 0; r < 4; ++r) {
        int t  = tile + w * 16 + g * 4 + r;
        int tc = t < T ? t : T - 1;
        pred[r] = t < T;
#pragma unroll
        for (int s = 0; s < A; ++s) nodes2[s][r] = idx[(long)tc * A + s];
    }
    if constexpr (!DUAL) __syncthreads();

#pragma unroll
    for (int j = 0; j < NT; ++j) {
        f32x4 acc = {0.f, 0.f, 0.f, 0.f};
#pragma unroll
        for (int kk = 0; kk < KS; ++kk) {
            F8 bf; bf.q = *(const uint4*)(W2base + swz(j * 16 + lr, kk * 32 + g * 8, D));
            acc = __builtin_amdgcn_mfma_f32_16x16x32_bf16(a2[kk], bf.b, acc, 0, 0, 0);
        }
        const int slot = j >> 2;
        const int coff = (j & 3) * 16 + lr;
#pragma unroll
        for (int r = 0; r < 4; ++r) {
            if (pred[r])
                unsafeAtomicAdd(dout + (long)nodes2[slot][r] * H + coff, acc[r] + bias2[j]);
        }
    }
}

// ---------------- update: fused segment-sum + 2-layer MLP ----------------
// MODE 0: SEG sequential (msgs sorted); MODE 1: SEG via ord; MODE 2: non-SEG.
// base(t) = base[t] + sums[t>>9] for MODE<=1 (scan_add folded away).
template<int MODE>
__global__ __launch_bounds__(512) void update_kernel(
    const float* __restrict__ ns, const u16* __restrict__ nsb,
    const float* __restrict__ sum,
    const u32* __restrict__ ord, const u32* __restrict__ base,
    const u32* __restrict__ sums,
    const u16* __restrict__ msg, int Mtot,
    const u16* __restrict__ wu1T, const float* __restrict__ bu1,
    const u16* __restrict__ wu2T, const float* __restrict__ bu2,
    float* __restrict__ out, int N)
{
    __shared__ __align__(16) u16 Wl[128 * 128 + 64 * 128];
    __shared__ __align__(16) u16 h[128 * 128];

    const int tid  = threadIdx.x;
    const int lane = tid & 63;
    const int w    = tid >> 6;
    const int g    = lane >> 4;
    const int lr   = lane & 15;

    {
        const uint4* s4 = (const uint4*)wu1T;
        uint4* d4 = (uint4*)Wl;
#pragma unroll
        for (int i = 0; i < 6; ++i) d4[i * 512 + tid] = s4[i * 512 + tid];
    }

    const int tile = blockIdx.x * 128;
    const int trow = tile + w * 16 + lr;
    const int tl   = trow < N ? trow : N - 1;

    bf16x8 a1[4];
    if constexpr (MODE <= 1) {
        const u32 s = base[tl] + sums[tl >> 9];
        const u32 e = (tl + 1 < N) ? (base[tl + 1] + sums[(tl + 1) >> 9]) : (u32)Mtot;
        float s0[8], s1[8];
#pragma unroll
        for (int j = 0; j < 8; ++j) { s0[j] = 0.f; s1[j] = 0.f; }
        for (u32 p = s; p < e; ++p) {
            const u16* row = msg + (size_t)(MODE == 1 ? ord[p] : p) * 64;
            F8 v0, v1;
            v0.q = *(const uint4*)(row + g * 8);
            v1.q = *(const uint4*)(row + 32 + g * 8);
#pragma unroll
            for (int j = 0; j < 8; ++j) { s0[j] += bf2f(v0.u[j]); s1[j] += bf2f(v1.u[j]); }
        }
        F8 t0, t1;
#pragma unroll
        for (int j = 0; j < 8; ++j) { t0.u[j] = f2bf(s0[j]); t1.u[j] = f2bf(s1[j]); }
        a1[0] = t0.b; a1[1] = t1.b;
    } else {
#pragma unroll
        for (int kk = 0; kk < 2; ++kk) {
            int k = kk * 32 + g * 8;
            const float* p = sum + (long)tl * H + k;
            float4 f0 = *(const float4*)p;
            float4 f1 = *(const float4*)(p + 4);
            F8 t;
            t.u[0] = f2bf(f0.x); t.u[1] = f2bf(f0.y); t.u[2] = f2bf(f0.z); t.u[3] = f2bf(f0.w);
            t.u[4] = f2bf(f1.x); t.u[5] = f2bf(f1.y); t.u[6] = f2bf(f1.z); t.u[7] = f2bf(f1.w);
            a1[kk] = t.b;
        }
    }
#pragma unroll
    for (int kk = 2; kk < 4; ++kk) {
        if constexpr (MODE <= 1) {
            const u16* prow = nsb + (long)tl * H;
            F8 t; t.q = *(const uint4*)(prow + (kk - 2) * 32 + g * 8);
            a1[kk] = t.b;
        } else {
            int k = (kk - 2) * 32 + g * 8;
            const float* p = ns + (long)tl * H + k;
            float4 f0 = *(const float4*)p;
            float4 f1 = *(const float4*)(p + 4);
            F8 t;
            t.u[0] = f2bf(f0.x); t.u[1] = f2bf(f0.y); t.u[2] = f2bf(f0.z); t.u[3] = f2bf(f0.w);
            t.u[4] = f2bf(f1.x); t.u[5] = f2bf(f1.y); t.u[6] = f2bf(f1.z); t.u[7] = f2bf(f1.w);
            a1[kk] = t.b;
        }
    }

    float bias1[8], bias2[4];
#pragma unroll
    for (int j = 0; j < 8; ++j) bias1[j] = bu1[j * 16 + lr];
#pragma unroll
    for (int j = 0; j < 4; ++j) bias2[j] = bu2[j * 16 + lr];

    __syncthreads();

#pragma unroll
    for (int j = 0; j < 8; ++j) {
        f32x4 acc = {0.f, 0.f, 0.f, 0.f};
#pragma unroll
        for (int kk = 0; kk < 4; ++kk) {
            F8 bf; bf.q = *(const uint4*)((const char*)Wl + swz(j * 16 + lr, kk * 32 + g * 8, 128));
            acc = __builtin_amdgcn_mfma_f32_16x16x32_bf16(a1[kk], bf.b, acc, 0, 0, 0);
        }
#pragma unroll
        for (int r = 0; r < 4; ++r) {
            float vv = acc[r] + bias1[j];
            vv = vv > 0.f ? vv : 0.f;
            int row = w * 16 + g * 4 + r;
            *(u16*)((char*)h + swz(row, j * 16 + lr, 128)) = f2bf(vv);
        }
    }

    bf16x8 a2[4];
#pragma unroll
    for (int kk = 0; kk < 4; ++kk) {
        int row = w * 16 + lr;
        F8 t; t.q = *(const uint4*)((const char*)h + swz(row, kk * 32 + g * 8, 128));
        a2[kk] = t.b;
    }

    const char* W2base = (const char*)(Wl + 128 * 128);
#pragma unroll
    for (int j = 0; j < 4; ++j) {
        f32x4 acc = {0.f, 0.f, 0.f, 0.f};
#pragma unroll
        for (int kk = 0; kk < 4; ++kk) {
            F8 bf; bf.q = *(const uint4*)(W2base + swz(j * 16 + lr, kk * 32 + g * 8, 128));
            acc = __builtin_amdgcn_mfma_f32_16x16x32_bf16(a2[kk], bf.b, acc, 0, 0, 0);
        }
#pragma unroll
        for (int r = 0; r < 4; ++r) {
            int t = tile + w * 16 + g * 4 + r;
            if (t < N) out[(long)t * H + j * 16 + lr] = acc[r] + bias2[j];
        }
    }
}

// ---------------- launcher ----------------
extern "C" void kernel_launch(void* const* d_in, const int* in_sizes, int n_in,
                              void* d_out, int out_size, void* d_ws, size_t ws_size,
                              hipStream_t stream) {
    const float* ns = (const float*)d_in[0];
    const int* idxs[3] = { (const int*)d_in[1], (const int*)d_in[6], (const int*)d_in[11] };
    const float* b1s[3] = { (const float*)d_in[3], (const float*)d_in[8], (const float*)d_in[13] };
    const float* b2s[3] = { (const float*)d_in[5], (const float*)d_in[10], (const float*)d_in[15] };
    const float* bu1 = (const float*)d_in[17];
    const float* bu2 = (const float*)d_in[19];

    const int N = in_sizes[0] / H;
    const int Ts[3] = { in_sizes[1], in_sizes[6] / 2, in_sizes[11] / 3 };
    const int Ms[3] = { Ts[0] * 1, Ts[1] * 2, Ts[2] * 3 };
    const long Mtot = (long)Ms[0] + Ms[1] + Ms[2];

    char* wsb = (char*)d_ws;
    auto AL = [](size_t x) { return (x + 255) & ~(size_t)255; };

    const unsigned O_W1R0 = 0;
    const unsigned O_W2R0 = O_W1R0 + 64 * 64 * 2;
    const unsigned O_W1R1 = O_W2R0 + 64 * 64 * 2;
    const unsigned O_W2R1 = O_W1R1 + 128 * 128 * 2;
    const unsigned O_W1R2 = O_W2R1 + 128 * 128 * 2;
    const unsigned O_W2R2 = O_W1R2 + 192 * 192 * 2;
    const unsigned O_WU1  = O_W2R2 + 192 * 192 * 2;
    const unsigned O_WU2  = O_WU1 + 128 * 128 * 2;
    const size_t  wEnd    = O_WU2 + 128 * 64 * 2;
    const unsigned wOff1[3] = { O_W1R0, O_W1R1, O_W1R2 };
    const unsigned wOff2[3] = { O_W2R0, O_W2R1, O_W2R2 };

    const int nb = (N + 511) / 512;

    const size_t O_CNT = AL(wEnd);                       // intra-block prefix after scan
    const size_t O_SUM = AL(O_CNT + (size_t)N * 4);
    const size_t O_PRE = AL(O_SUM + (size_t)nb * 4);
    const size_t O_ORD = AL(O_PRE + (size_t)Mtot * 4);
    const size_t O_NSB = AL(O_ORD + (size_t)Mtot * 4);
    const size_t nsLen = (size_t)N * H * 2;
    const size_t O_MSG = AL(O_NSB + nsLen);
    const size_t O_MSGS = AL(O_MSG + (size_t)Mtot * 128);
    const size_t need1 = O_MSGS;                          // ord path
    const size_t need2 = O_MSGS + (size_t)Mtot * 128;     // scatter path

    const bool sorted2 = (nb <= 512) && (ws_size >= need2);
    const bool sorted1 = (nb <= 512) && (ws_size >= need1);

    Segs segs;
    segs.s[0] = {(const float*)d_in[2],  O_W1R0, 64, 64};
    segs.s[1] = {(const float*)d_in[4],  O_W2R0, 64, 64};
    segs.s[2] = {(const float*)d_in[7],  O_W1R1, 128, 128};
    segs.s[3] = {(const float*)d_in[9],  O_W2R1, 128, 128};
    segs.s[4] = {(const float*)d_in[12], O_W1R2, 192, 192};
    segs.s[5] = {(const float*)d_in[14], O_W2R2, 192, 192};
    segs.s[6] = {(const float*)d_in[16], O_WU1, 128, 128};
    segs.s[7] = {(const float*)d_in[18], O_WU2, 128, 64};

    float* dout = (float*)d_out;
    const u16* W1[3] = { (const u16*)(wsb + wOff1[0]), (const u16*)(wsb + wOff1[1]), (const u16*)(wsb + wOff1[2]) };
    const u16* W2[3] = { (const u16*)(wsb + wOff2[0]), (const u16*)(wsb + wOff2[1]), (const u16*)(wsb + wOff2[2]) };

    auto gT = [](int T) { return (T + 127) / 128; };

    if (sorted1 || sorted2) {
        u32* cnt = (u32*)(wsb + O_CNT);
        u32* sums = (u32*)(wsb + O_SUM);
        u32* pre = (u32*)(wsb + O_PRE);
        u32* ord = (u32*)(wsb + O_ORD);
        u16* nsbp = (u16*)(wsb + O_NSB);
        u16* msgu = (u16*)(wsb + O_MSG);
        u16* msgs = (u16*)(wsb + O_MSGS);

        PrepA pp;
        pp.nsrc = (const float4*)ns; pp.ndst = (ushort4*)nsbp; pp.n4 = N * H / 4;
        pp.segs = segs; pp.wout = wsb; pp.cnt = cnt; pp.N = N;
        prep_kernel<<<dim3(448, 3), 256, 0, stream>>>(pp);

        const int nb0 = gT(Ts[0]), nb1 = gT(Ts[1]), nb2 = gT(Ts[2]);
        const int nmsg = nb0 + nb1 + nb2;
        int NR = nmsg / 3; if (NR > 1024) NR = 1024; if (NR < 1) NR = 1;
        const int striped = (nmsg >= 3 * NR) ? 1 : 0;
        const int NTOT = NR + nmsg;

        MegaA ma;
        ma.nsb = nsbp;
        ma.idx0 = idxs[0]; ma.idx1 = idxs[1]; ma.idx2 = idxs[2];
        ma.m0 = Ms[0]; ma.m1 = Ms[1]; ma.m2 = Ms[2];
        ma.t0 = Ts[0]; ma.t1 = Ts[1]; ma.t2 = Ts[2];
        ma.cnt = cnt; ma.pre = pre;
        ma.w10 = W1[0]; ma.w20 = W2[0];
        ma.w11 = W1[1]; ma.w21 = W2[1];
        ma.w12 = W1[2]; ma.w22 = W2[2];
        ma.b10 = b1s[0]; ma.b20 = b2s[0];
        ma.b11 = b1s[1]; ma.b21 = b2s[1];
        ma.b12 = b1s[2]; ma.b22 = b2s[2];
        ma.msgu = msgu;
        ma.nrank = NR; ma.nb2 = nb2; ma.nb1 = nb1; ma.nb0 = nb0; ma.striped = striped;
        mega_kernel<<<NTOT, 512, 0, stream>>>(ma);

        scan_blocks<<<nb, 512, 0, stream>>>(cnt, sums, N);
        scan_sums<<<1, 512, 0, stream>>>(sums, nb);

        if (sorted2) {
            Scat sc;
            sc.idx0 = idxs[0]; sc.idx1 = idxs[1]; sc.idx2 = idxs[2];
            sc.m0 = Ms[0]; sc.m1 = Ms[1]; sc.m2 = Ms[2];
            sc.base = cnt; sc.sums = sums; sc.pre = pre;
            sc.msgu = msgu; sc.msgs = msgs;
            scatter_msg<<<2048, 256, 0, stream>>>(sc);

            update_kernel<0><<<(N + 127) / 128, 512, 0, stream>>>(
                ns, nsbp, nullptr, nullptr, cnt, sums, msgs, (int)Mtot,
                (const u16*)(wsb + O_WU1), bu1, (const u16*)(wsb + O_WU2), bu2, dout, N);
        } else {
            OFix fx;
            fx.idx0 = idxs[0]; fx.idx1 = idxs[1]; fx.idx2 = idxs[2];
            fx.m0 = Ms[0]; fx.m1 = Ms[1]; fx.m2 = Ms[2];
            fx.base = cnt; fx.sums = sums; fx.pre = pre; fx.ord = ord;
            ord_fix<<<2048, 256, 0, stream>>>(fx);

            update_kernel<1><<<(N + 127) / 128, 512, 0, stream>>>(
                ns, nsbp, nullptr, ord, cnt, sums, msgu, (int)Mtot,
                (const u16*)(wsb + O_WU1), bu1, (const u16*)(wsb + O_WU2), bu2, dout, N);
        }
    } else {
        conv_weights<<<dim3(36, 8), 256, 0, stream>>>(segs, wsb);
        hipMemsetAsync(dout, 0, (size_t)N * H * sizeof(float), stream);
        for (int r = 0; r < 3; ++r) {
            const int T = Ts[r], nbl = gT(T);
            if (r == 0) rel_kernel<1><<<nbl, 512, 0, stream>>>(ns, idxs[0], W1[0], b1s[0], W2[0], b2s[0], dout, T);
            if (r == 1) rel_kernel<2><<<nbl, 512, 0, stream>>>(ns, idxs[1], W1[1], b1s[1], W2[1], b2s[1], dout, T);
            if (r == 2) rel_kernel<3><<<nbl, 512, 0, stream>>>(ns, idxs[2], W1[2], b1s[2], W2[2], b2s[2], dout, T);
        }
        update_kernel<2><<<(N + 127) / 128, 512, 0, stream>>>(
            ns, nullptr, dout, nullptr, nullptr, nullptr, nullptr, 0,
            (const u16*)(wsb + O_WU1), bu1, (const u16*)(wsb + O_WU2), bu2, dout, N);
    }
}